// Round 6
// baseline (2868.829 us; speedup 1.0000x reference)
//
#include <hip/hip_runtime.h>

// VectorQuantizer: z (32,64,64,64) fp32, embedding_w (2048,64) fp32.
// Outputs concat: quantized_out (32,64,64,64) | indices (32,64,64) as float | loss (1)
//
// Numerics: bit-exact replication of the numpy fp32 reference (verified R1-R5, absmax 0):
//   S_n = pairwise64(z_n^2), b_k = pairwise64(w_k^2)  (numpy pairwise_sum order)
//   C_nk = one sequential fp32 FMA chain over c=0..63 ascending per (n,k)
//   d = fp32(fp32(S + b) - fp32(2*C)), argmin first-index tie-break.
//
// R6: scalar v_fma_f32 with w as direct SGPR operand (v_fma v,v,s,v — one SGPR
// source is legal). Rate model from R2/R4 counters: scalar fp32 FMA is full-rate
// (157.3 TF); v_pk_fma_f32 is 4cyc = no gain, and its splats cost movs. So:
//  - z tile in LDS, row-major stride 66 (8B-aligned rows; b64 reads conflict-free
//    per 16-lane phase; staging 2-way only)
//  - w + bsum via wave-uniform s_load (kwave from readfirstlane; R4-proven)
//  - 128 rows/block -> ~35 KB LDS -> 4 blocks/CU = 16 waves/CU (R4 had 6.5)
//  - per-wave: 512 codes x 128 rows; thread: rows {l, l+64} x 8 codes/group
//  - argmin merge: packed key (d_bits<<32|k) atomicMin in LDS (d>0; R3-proven)
//  - fused epilogue (indices, STE quantized, fp64 loss partial)
// R5 lesson: NEVER force uniform data onto the per-lane vector path (spills +
// 2.3 GB refetch). No opaque-VGPR tricks here.

#define KCODES   2048
#define CDIM     64
#define OUT_Q    0
#define OUT_IDX  8388608
#define OUT_LOSS 8519680
#define STR      66         // LDS row stride (floats): rows 8B-aligned, phase-conflict-free b64

typedef float f2 __attribute__((ext_vector_type(2)));

__device__ __forceinline__ float pairwise64(const float a[64]) {
    float r[8];
#pragma unroll
    for (int j = 0; j < 8; ++j) r[j] = a[j];
#pragma unroll
    for (int m = 1; m < 8; ++m)
#pragma unroll
        for (int j = 0; j < 8; ++j) r[j] = __fadd_rn(r[j], a[m * 8 + j]);
    float s01 = __fadd_rn(r[0], r[1]);
    float s23 = __fadd_rn(r[2], r[3]);
    float s45 = __fadd_rn(r[4], r[5]);
    float s67 = __fadd_rn(r[6], r[7]);
    return __fadd_rn(__fadd_rn(s01, s23), __fadd_rn(s45, s67));
}

__device__ __forceinline__ float fc(const float4& v, int i) {
    return i == 0 ? v.x : (i == 1 ? v.y : (i == 2 ? v.z : v.w));
}

// ---------------- kernel A: b_k = pairwise64(w_k^2) ----------------
__global__ __launch_bounds__(256) void vq_bsum(const float* __restrict__ w,
                                               float* __restrict__ bsum) {
    int k = blockIdx.x * 256 + threadIdx.x;
    const float4* wr = (const float4*)(w + (size_t)k * CDIM);
    float a[64];
#pragma unroll
    for (int m = 0; m < 16; ++m) {
        float4 v = wr[m];
        a[4 * m + 0] = __fmul_rn(v.x, v.x);
        a[4 * m + 1] = __fmul_rn(v.y, v.y);
        a[4 * m + 2] = __fmul_rn(v.z, v.z);
        a[4 * m + 3] = __fmul_rn(v.w, v.w);
    }
    bsum[k] = pairwise64(a);
}

// ---------------- kernel B: main VQ (fused argmin + epilogue) ----------------
// grid 1024 blocks x 256 thr. Block = 128 rows (2 h-values). Wave wv sweeps
// codes [wv*512, wv*512+512). Thread (lane l) owns rows l and l+64.
__global__ __launch_bounds__(256, 4) void vq_main(const float* __restrict__ z,
                                                  const float* __restrict__ w,
                                                  const float* __restrict__ bsum,
                                                  float* __restrict__ out,
                                                  float* __restrict__ partial) {
    __shared__ float zsh[128 * STR];                // 33 KB, zsh[row][dim]
    __shared__ float Ss[128];
    __shared__ unsigned long long skey[128];
    __shared__ double lred[4];

    const int t  = threadIdx.x;
    const int l  = t & 63;
    const int bb = blockIdx.x;                      // 0..1023; rows [bb*128, +128)
    const size_t zbase = (size_t)(bb >> 5) * 262144 + (size_t)(bb & 31) * 128;

    // ---- stage z tile: zsh[r][c] = z[b][c][rows] (transpose via f2 loads) ----
#pragma unroll
    for (int m = 0; m < 16; ++m) {
        int i4 = m * 256 + t;                       // 0..4095 f2's
        int c  = i4 >> 6;                           // 0..63
        int r2 = i4 & 63;                           // row pair
        f2 v = *(const f2*)(z + zbase + (size_t)c * 4096 + 2 * r2);
        zsh[(2 * r2) * STR + c]     = v.x;
        zsh[(2 * r2 + 1) * STR + c] = v.y;
    }
    __syncthreads();

    // ---- S per row (numpy pairwise of squares); init argmin keys ----
    if (t < 128) {
        float a[64];
#pragma unroll
        for (int c = 0; c < 64; ++c) {
            float v = zsh[t * STR + c];
            a[c] = __fmul_rn(v, v);
        }
        Ss[t] = pairwise64(a);
        skey[t] = 0xFFFFFFFFFFFFFFFFull;
    }
    __syncthreads();

    const float SA = Ss[l];
    const float SB = Ss[l + 64];

    // wave-uniform code range -> all w/bsum accesses scalarize to s_load
    const int kwave = __builtin_amdgcn_readfirstlane(t >> 6) * 512;

    float dminA = __builtin_inff(), dminB = __builtin_inff();
    int   kminA = 0, kminB = 0;

    const int zoffA = l * STR;
    const int zoffB = (l + 64) * STR;

    for (int ks = 0; ks < 64; ++ks) {
        const int k0 = kwave + ks * 8;              // wave-uniform
        const float* wk = w + (size_t)k0 * CDIM;

        float accA[8], accB[8];
#pragma unroll
        for (int j = 0; j < 8; ++j) { accA[j] = 0.f; accB[j] = 0.f; }

#pragma unroll
        for (int st = 0; st < 16; ++st) {
            const int c0 = st * 4;
            // wave-uniform addresses -> s_load_dwordx4 (SGPRs, scalar pipe)
            float4 wc[8];
#pragma unroll
            for (int j = 0; j < 8; ++j)
                wc[j] = *(const float4*)(wk + (size_t)j * CDIM + c0);

            // z rows, dims c0..c0+3 (two f2 loads per row; 8B-aligned)
            f2 zA0 = *(const f2*)&zsh[zoffA + c0];
            f2 zA1 = *(const f2*)&zsh[zoffA + c0 + 2];
            f2 zB0 = *(const f2*)&zsh[zoffB + c0];
            f2 zB1 = *(const f2*)&zsh[zoffB + c0 + 2];

#pragma unroll
            for (int j = 0; j < 8; ++j) {
                // dims ascending -> one sequential chain per (row, code): bit-exact.
                // v_fma_f32 vacc, vz, s_w, vacc  (SGPR operand, no splat movs)
                accA[j] = __builtin_fmaf(zA0.x, wc[j].x, accA[j]);
                accA[j] = __builtin_fmaf(zA0.y, wc[j].y, accA[j]);
                accA[j] = __builtin_fmaf(zA1.x, wc[j].z, accA[j]);
                accA[j] = __builtin_fmaf(zA1.y, wc[j].w, accA[j]);
                accB[j] = __builtin_fmaf(zB0.x, wc[j].x, accB[j]);
                accB[j] = __builtin_fmaf(zB0.y, wc[j].y, accB[j]);
                accB[j] = __builtin_fmaf(zB1.x, wc[j].z, accB[j]);
                accB[j] = __builtin_fmaf(zB1.y, wc[j].w, accB[j]);
            }
        }

        // d = fp32((S + b) - 2*C); strict < keeps earliest k (k ascending)
        const float4 bq0 = *(const float4*)(bsum + k0);     // uniform -> s_load
        const float4 bq1 = *(const float4*)(bsum + k0 + 4);
#pragma unroll
        for (int j = 0; j < 8; ++j) {
            const float bj = j < 4 ? fc(bq0, j) : fc(bq1, j - 4);
            const float dA = __fsub_rn(__fadd_rn(SA, bj), __fadd_rn(accA[j], accA[j]));
            const float dB = __fsub_rn(__fadd_rn(SB, bj), __fadd_rn(accB[j], accB[j]));
            const int kg = k0 + j;
            if (dA < dminA) { dminA = dA; kminA = kg; }
            if (dB < dminB) { dminB = dB; kminB = kg; }
        }
    }

    // ---- merge per-row argmin across the 4 waves (packed key, LDS atomic) ----
    atomicMin(&skey[l],      ((unsigned long long)__float_as_uint(dminA) << 32) | (unsigned int)kminA);
    atomicMin(&skey[l + 64], ((unsigned long long)__float_as_uint(dminB) << 32) | (unsigned int)kminB);
    __syncthreads();

    // ---- epilogue ----
    if (t < 128)
        out[OUT_IDX + (size_t)bb * 128 + t] = (float)(int)(skey[t] & 0xFFFFFFFFull);

    double lacc = 0.0;
#pragma unroll
    for (int m = 0; m < 32; ++m) {
        int i = m * 256 + t;                        // 0..8191
        int c = i >> 7;                             // 0..63
        int r = i & 127;
        int kq = (int)(skey[r] & 0xFFFFFFFFull);
        float zv = zsh[r * STR + c];
        float q  = w[(size_t)kq * CDIM + c];
        float d1  = __fsub_rn(q, zv);               // quantized - zp
        float val = __fadd_rn(zv, d1);              // zp + (q - zp)
        out[OUT_Q + zbase + (size_t)c * 4096 + r] = val;
        lacc += (double)__fmul_rn(d1, d1);
    }

#pragma unroll
    for (int off = 1; off < 64; off <<= 1) lacc += __shfl_xor(lacc, off, 64);
    if ((t & 63) == 0) lred[t >> 6] = lacc;
    __syncthreads();
    if (t == 0) {
        double tot = lred[0] + lred[1] + lred[2] + lred[3];
        partial[bb] = (float)(tot * (0.25 / 8388608.0));
    }
}

// ---------------- kernel C: reduce loss partials (1024) ----------------
__global__ __launch_bounds__(256) void vq_loss(const float* __restrict__ partial,
                                               float* __restrict__ out) {
    int t = threadIdx.x;
    double s = 0.0;
#pragma unroll
    for (int m = 0; m < 4; ++m) s += (double)partial[t + 256 * m];
#pragma unroll
    for (int off = 1; off < 64; off <<= 1) s += __shfl_xor(s, off, 64);
    __shared__ double sr[4];
    if ((t & 63) == 0) sr[t >> 6] = s;
    __syncthreads();
    if (t == 0) out[OUT_LOSS] = (float)(sr[0] + sr[1] + sr[2] + sr[3]);
}

extern "C" void kernel_launch(void* const* d_in, const int* in_sizes, int n_in,
                              void* d_out, int out_size, void* d_ws, size_t ws_size,
                              hipStream_t stream) {
    (void)in_sizes; (void)n_in; (void)out_size; (void)ws_size;
    const float* z = (const float*)d_in[0];
    const float* w = (const float*)d_in[1];
    float* out     = (float*)d_out;

    float* bsum    = (float*)d_ws;                  // 2048 floats
    float* partial = bsum + KCODES;                 // 1024 floats

    vq_bsum<<<8, 256, 0, stream>>>(w, bsum);
    vq_main<<<1024, 256, 0, stream>>>(z, w, bsum, out, partial);
    vq_loss<<<1, 256, 0, stream>>>(partial, out);
}

// Round 7
// 861.139 us; speedup vs baseline: 3.3314x; 3.3314x over previous
//
#include <hip/hip_runtime.h>

// VectorQuantizer: z (32,64,64,64) fp32, embedding_w (2048,64) fp32.
// Outputs concat: quantized_out (32,64,64,64) | indices (32,64,64) as float | loss (1)
//
// Numerics: bit-exact replication of the numpy fp32 reference (verified R1-R6, absmax 0):
//   S_n = pairwise64(z_n^2), b_k = pairwise64(w_k^2)  (numpy pairwise_sum order)
//   C_nk = one sequential fp32 FMA chain over c=0..63 ascending per (n,k)
//   d = fp32(fp32(S + b) - fp32(2*C)), argmin first-index tie-break.
//
// R7 = R4's verified structure (448 us; pk-fma formed, no spills, splats folded)
// with ONE change: half the tile. 64 row-pairs per block (128 rows), LDS 34 KB
// -> 4 blocks/CU = 16 waves/CU (R4: 67 KB -> 2 blocks -> 6.5 waves/CU), to hide
// the lgkm (s_load/ds_read) waits that were R4's 33% idle. Inner loop kept
// byte-identical in shape: wc loaded per-j inside the loop (R6's wc[8] array
// hoist + launch_bounds(256,4) caused scratch spills + 9 GB refetch — never
// hoist uniform loads into arrays; launch_bounds left loose at (256,3)).
// R5 lesson: never force uniform data onto the per-lane vector path.

#define KCODES   2048
#define CDIM     64
#define OUT_Q    0
#define OUT_IDX  8388608
#define OUT_LOSS 8519680
#define PSTR     132        // floats per pair-row: 64 dims * 2 + 4 pad

typedef float f2 __attribute__((ext_vector_type(2)));

__device__ __forceinline__ f2 fma2(f2 a, f2 b, f2 c) {
#if __has_builtin(__builtin_elementwise_fma)
    return __builtin_elementwise_fma(a, b, c);
#else
    f2 r; r.x = __builtin_fmaf(a.x, b.x, c.x); r.y = __builtin_fmaf(a.y, b.y, c.y);
    return r;
#endif
}

__device__ __forceinline__ float pairwise64(const float a[64]) {
    float r[8];
#pragma unroll
    for (int j = 0; j < 8; ++j) r[j] = a[j];
#pragma unroll
    for (int m = 1; m < 8; ++m)
#pragma unroll
        for (int j = 0; j < 8; ++j) r[j] = __fadd_rn(r[j], a[m * 8 + j]);
    float s01 = __fadd_rn(r[0], r[1]);
    float s23 = __fadd_rn(r[2], r[3]);
    float s45 = __fadd_rn(r[4], r[5]);
    float s67 = __fadd_rn(r[6], r[7]);
    return __fadd_rn(__fadd_rn(s01, s23), __fadd_rn(s45, s67));
}

__device__ __forceinline__ float fc(const float4& v, int i) {
    return i == 0 ? v.x : (i == 1 ? v.y : (i == 2 ? v.z : v.w));
}

// ---------------- kernel A: b_k = pairwise64(w_k^2) ----------------
__global__ __launch_bounds__(256) void vq_bsum(const float* __restrict__ w,
                                               float* __restrict__ bsum) {
    int k = blockIdx.x * 256 + threadIdx.x;
    const float4* wr = (const float4*)(w + (size_t)k * CDIM);
    float a[64];
#pragma unroll
    for (int m = 0; m < 16; ++m) {
        float4 v = wr[m];
        a[4 * m + 0] = __fmul_rn(v.x, v.x);
        a[4 * m + 1] = __fmul_rn(v.y, v.y);
        a[4 * m + 2] = __fmul_rn(v.z, v.z);
        a[4 * m + 3] = __fmul_rn(v.w, v.w);
    }
    bsum[k] = pairwise64(a);
}

// ---------------- kernel B: main VQ (fused argmin + epilogue) ----------------
// grid 1024 x 256 thr. Block = 128 rows (64 pairs). Wave wv sweeps codes
// [wv*512, wv*512+512). Lane l owns row-pair l (rows 2l, 2l+1).
__global__ __launch_bounds__(256, 3) void vq_main(const float* __restrict__ z,
                                                  const float* __restrict__ w,
                                                  const float* __restrict__ bsum,
                                                  float* __restrict__ out,
                                                  float* __restrict__ partial) {
    __shared__ float zsh[64 * PSTR];                // 33.8 KB: zsh[pair][dim] as f2
    __shared__ float Ss[128];
    __shared__ unsigned long long skey[128];
    __shared__ double lred[4];

    const int t  = threadIdx.x;
    const int l  = t & 63;                          // lane
    const int bb = blockIdx.x;                      // 0..1023; rows [bb*128, +128)
    const size_t zbase = (size_t)(bb >> 5) * 262144 + (size_t)(bb & 31) * 128;

    // ---- stage z tile: zsh[p][c] = (z_row{2p}_c, z_row{2p+1}_c) ----
#pragma unroll
    for (int m = 0; m < 16; ++m) {
        int i = m * 256 + t;                        // 0..4095 f2's
        int p = i & 63;
        int c = i >> 6;
        f2 v = *(const f2*)(z + zbase + (size_t)c * 4096 + 2 * p);
        *(f2*)&zsh[p * PSTR + 2 * c] = v;
    }
    __syncthreads();

    // ---- S per row (numpy pairwise of squares); init argmin keys ----
    if (t < 128) {
        float a[64];
        const int pb = (t >> 1) * PSTR + (t & 1);
#pragma unroll
        for (int c = 0; c < 64; ++c) {
            float v = zsh[pb + 2 * c];
            a[c] = __fmul_rn(v, v);
        }
        Ss[t] = pairwise64(a);
        skey[t] = 0xFFFFFFFFFFFFFFFFull;
    }
    __syncthreads();

    f2 Sp;
    Sp.x = Ss[2 * l];
    Sp.y = Ss[2 * l + 1];

    // wave-uniform code range: wave wv handles codes [wv*512, wv*512+512)
    const int kwave = __builtin_amdgcn_readfirstlane(t >> 6) * 512;

    float dmin0 = __builtin_inff(), dmin1 = __builtin_inff();
    int   kmin0 = 0, kmin1 = 0;

    const int zoff = l * PSTR;

    for (int ks = 0; ks < 64; ++ks) {
        const int k0 = kwave + ks * 8;              // wave-uniform
        const float* wk = w + (size_t)k0 * CDIM;

        f2 acc0[8];
#pragma unroll
        for (int j = 0; j < 8; ++j) acc0[j] = (f2)0.f;

#pragma unroll
        for (int st = 0; st < 16; ++st) {
            const int c0 = st * 4;

            // z row-pair, dims c0..c0+3 (x,y = dim c; z,w = dim c+1)
            float4 a0 = *(const float4*)&zsh[zoff + 2 * c0];
            float4 a1 = *(const float4*)&zsh[zoff + 2 * c0 + 4];
            f2 aL0; aL0.x = a0.x; aL0.y = a0.y;     // pair @ c0
            f2 aH0; aH0.x = a0.z; aH0.y = a0.w;     // pair @ c0+1
            f2 aL1; aL1.x = a1.x; aL1.y = a1.y;     // pair @ c0+2
            f2 aH1; aH1.x = a1.z; aH1.y = a1.w;     // pair @ c0+3

#pragma unroll
            for (int j = 0; j < 8; ++j) {
                // wave-uniform address -> s_load_dwordx4 (scalar pipe);
                // loaded per-j (NOT hoisted into an array — see R6 lesson)
                const float4 wc = *(const float4*)(wk + (size_t)j * CDIM + c0);
                f2 w0 = (f2)(wc.x);                 // splat -> op_sel fold
                f2 w1 = (f2)(wc.y);
                f2 w2 = (f2)(wc.z);
                f2 w3 = (f2)(wc.w);
                // dims ascending -> sequential chain per (row, code), bit-exact
                acc0[j] = fma2(aL0, w0, acc0[j]);
                acc0[j] = fma2(aH0, w1, acc0[j]);
                acc0[j] = fma2(aL1, w2, acc0[j]);
                acc0[j] = fma2(aH1, w3, acc0[j]);
            }
        }

        // d = fp32((S + b) - 2*C); strict < keeps earliest k (k ascending)
        const float4 bq0 = *(const float4*)(bsum + k0);      // uniform -> s_load
        const float4 bq1 = *(const float4*)(bsum + k0 + 4);
#pragma unroll
        for (int j = 0; j < 8; ++j) {
            float bj = j < 4 ? fc(bq0, j) : fc(bq1, j - 4);
            f2 bb2 = (f2)(bj);
            f2 dA = (Sp + bb2) - (acc0[j] + acc0[j]);
            int kg = k0 + j;
            if (dA.x < dmin0) { dmin0 = dA.x; kmin0 = kg; }
            if (dA.y < dmin1) { dmin1 = dA.y; kmin1 = kg; }
        }
    }

    // ---- merge per-row argmin across the 4 waves (packed key, LDS atomic) ----
    atomicMin(&skey[2 * l],     ((unsigned long long)__float_as_uint(dmin0) << 32) | (unsigned int)kmin0);
    atomicMin(&skey[2 * l + 1], ((unsigned long long)__float_as_uint(dmin1) << 32) | (unsigned int)kmin1);
    __syncthreads();

    // ---- epilogue ----
    if (t < 128)
        out[OUT_IDX + (size_t)bb * 128 + t] = (float)(int)(skey[t] & 0xFFFFFFFFull);

    double lacc = 0.0;
#pragma unroll
    for (int m = 0; m < 32; ++m) {
        int i = m * 256 + t;                        // 0..8191
        int c = i >> 7;                             // 0..63
        int r = i & 127;
        int kq = (int)(skey[r] & 0xFFFFFFFFull);
        float zv = zsh[(r >> 1) * PSTR + (r & 1) + 2 * c];
        float q  = w[(size_t)kq * CDIM + c];
        float d1  = __fsub_rn(q, zv);               // quantized - zp
        float val = __fadd_rn(zv, d1);              // zp + (q - zp)
        out[OUT_Q + zbase + (size_t)c * 4096 + r] = val;
        lacc += (double)__fmul_rn(d1, d1);
    }

#pragma unroll
    for (int off = 1; off < 64; off <<= 1) lacc += __shfl_xor(lacc, off, 64);
    if ((t & 63) == 0) lred[t >> 6] = lacc;
    __syncthreads();
    if (t == 0) {
        double tot = lred[0] + lred[1] + lred[2] + lred[3];
        partial[bb] = (float)(tot * (0.25 / 8388608.0));
    }
}

// ---------------- kernel C: reduce loss partials (1024) ----------------
__global__ __launch_bounds__(256) void vq_loss(const float* __restrict__ partial,
                                               float* __restrict__ out) {
    int t = threadIdx.x;
    double s = 0.0;
#pragma unroll
    for (int m = 0; m < 4; ++m) s += (double)partial[t + 256 * m];
#pragma unroll
    for (int off = 1; off < 64; off <<= 1) s += __shfl_xor(s, off, 64);
    __shared__ double sr[4];
    if ((t & 63) == 0) sr[t >> 6] = s;
    __syncthreads();
    if (t == 0) out[OUT_LOSS] = (float)(sr[0] + sr[1] + sr[2] + sr[3]);
}

extern "C" void kernel_launch(void* const* d_in, const int* in_sizes, int n_in,
                              void* d_out, int out_size, void* d_ws, size_t ws_size,
                              hipStream_t stream) {
    (void)in_sizes; (void)n_in; (void)out_size; (void)ws_size;
    const float* z = (const float*)d_in[0];
    const float* w = (const float*)d_in[1];
    float* out     = (float*)d_out;

    float* bsum    = (float*)d_ws;                  // 2048 floats
    float* partial = bsum + KCODES;                 // 1024 floats

    vq_bsum<<<8, 256, 0, stream>>>(w, bsum);
    vq_main<<<1024, 256, 0, stream>>>(z, w, bsum, out, partial);
    vq_loss<<<1, 256, 0, stream>>>(partial, out);
}

// Round 8
// 740.368 us; speedup vs baseline: 3.8749x; 1.1631x over previous
//
#include <hip/hip_runtime.h>

// VectorQuantizer: z (32,64,64,64) fp32, embedding_w (2048,64) fp32.
// Outputs concat: quantized_out (32,64,64,64) | indices (32,64,64) as float | loss (1)
//
// Numerics: bit-exact replication of the numpy fp32 reference (verified R1-R7, absmax 0):
//   S_n = pairwise64(z_n^2), b_k = pairwise64(w_k^2)  (numpy pairwise_sum order)
//   C_nk = one sequential fp32 FMA chain over c=0..63 ascending per (n,k)
//   d = fp32(fp32(S + b) - fp32(2*C)), argmin first-index tie-break.
//
// R8 = R7's skeleton (128 rows/block, 34 KB LDS -> 4 blocks/CU, lane owns row-
// pair l, wave sweeps 512 codes, LDS-atomicMin merge, fused epilogue) with the
// inner loop reshaped to 8-dim steps per code: per code j, two adjacent
// s_load_dwordx4 (merge toward dwordx8) feed 8 sequential fma2 (32 VALU cyc)
// -> 4x more FMA per scalar-load than R7, and per-code d/argmin amortized.
// Dim order within each (row,code) chain stays c ascending -> bit-exact.
// Lessons kept: no launch-bounds squeeze (R6), no arrays of global-loaded
// data (R5/R6), w only via provably wave-uniform addresses (R5).

#define KCODES   2048
#define CDIM     64
#define OUT_Q    0
#define OUT_IDX  8388608
#define OUT_LOSS 8519680
#define PSTR     132        // floats per pair-row: 64 dims * 2 + 4 pad (lane stride 4 banks)

typedef float f2 __attribute__((ext_vector_type(2)));

__device__ __forceinline__ f2 fma2(f2 a, f2 b, f2 c) {
#if __has_builtin(__builtin_elementwise_fma)
    return __builtin_elementwise_fma(a, b, c);
#else
    f2 r; r.x = __builtin_fmaf(a.x, b.x, c.x); r.y = __builtin_fmaf(a.y, b.y, c.y);
    return r;
#endif
}

__device__ __forceinline__ float pairwise64(const float a[64]) {
    float r[8];
#pragma unroll
    for (int j = 0; j < 8; ++j) r[j] = a[j];
#pragma unroll
    for (int m = 1; m < 8; ++m)
#pragma unroll
        for (int j = 0; j < 8; ++j) r[j] = __fadd_rn(r[j], a[m * 8 + j]);
    float s01 = __fadd_rn(r[0], r[1]);
    float s23 = __fadd_rn(r[2], r[3]);
    float s45 = __fadd_rn(r[4], r[5]);
    float s67 = __fadd_rn(r[6], r[7]);
    return __fadd_rn(__fadd_rn(s01, s23), __fadd_rn(s45, s67));
}

__device__ __forceinline__ float fc(const float4& v, int i) {
    return i == 0 ? v.x : (i == 1 ? v.y : (i == 2 ? v.z : v.w));
}

// ---------------- kernel A: b_k = pairwise64(w_k^2) ----------------
__global__ __launch_bounds__(256) void vq_bsum(const float* __restrict__ w,
                                               float* __restrict__ bsum) {
    int k = blockIdx.x * 256 + threadIdx.x;
    const float4* wr = (const float4*)(w + (size_t)k * CDIM);
    float a[64];
#pragma unroll
    for (int m = 0; m < 16; ++m) {
        float4 v = wr[m];
        a[4 * m + 0] = __fmul_rn(v.x, v.x);
        a[4 * m + 1] = __fmul_rn(v.y, v.y);
        a[4 * m + 2] = __fmul_rn(v.z, v.z);
        a[4 * m + 3] = __fmul_rn(v.w, v.w);
    }
    bsum[k] = pairwise64(a);
}

// ---------------- kernel B: main VQ (fused argmin + epilogue) ----------------
// grid 1024 x 256 thr. Block = 128 rows (64 pairs). Wave wv sweeps codes
// [wv*512, wv*512+512). Lane l owns row-pair l (rows 2l, 2l+1).
__global__ __launch_bounds__(256, 3) void vq_main(const float* __restrict__ z,
                                                  const float* __restrict__ w,
                                                  const float* __restrict__ bsum,
                                                  float* __restrict__ out,
                                                  float* __restrict__ partial) {
    __shared__ float zsh[64 * PSTR];                // 33.8 KB: zsh[pair][dim] as f2
    __shared__ float Ss[128];
    __shared__ unsigned long long skey[128];
    __shared__ double lred[4];

    const int t  = threadIdx.x;
    const int l  = t & 63;                          // lane
    const int bb = blockIdx.x;                      // 0..1023; rows [bb*128, +128)
    const size_t zbase = (size_t)(bb >> 5) * 262144 + (size_t)(bb & 31) * 128;

    // ---- stage z tile: zsh[p][c] = (z_row{2p}_c, z_row{2p+1}_c) ----
#pragma unroll
    for (int m = 0; m < 16; ++m) {
        int i = m * 256 + t;                        // 0..4095 f2's
        int p = i & 63;
        int c = i >> 6;
        f2 v = *(const f2*)(z + zbase + (size_t)c * 4096 + 2 * p);
        *(f2*)&zsh[p * PSTR + 2 * c] = v;
    }
    __syncthreads();

    // ---- S per row (numpy pairwise of squares); init argmin keys ----
    if (t < 128) {
        float a[64];
        const int pb = (t >> 1) * PSTR + (t & 1);
#pragma unroll
        for (int c = 0; c < 64; ++c) {
            float v = zsh[pb + 2 * c];
            a[c] = __fmul_rn(v, v);
        }
        Ss[t] = pairwise64(a);
        skey[t] = 0xFFFFFFFFFFFFFFFFull;
    }
    __syncthreads();

    f2 Sp;
    Sp.x = Ss[2 * l];
    Sp.y = Ss[2 * l + 1];

    // wave-uniform code range: wave wv handles codes [wv*512, wv*512+512)
    const int kwave = __builtin_amdgcn_readfirstlane(t >> 6) * 512;

    float dmin0 = __builtin_inff(), dmin1 = __builtin_inff();
    int   kmin0 = 0, kmin1 = 0;

    const int zoff = l * PSTR;

    for (int ks = 0; ks < 64; ++ks) {
        const int k0 = kwave + ks * 8;              // wave-uniform
        const float* wk = w + (size_t)k0 * CDIM;

        f2 acc0[8];
#pragma unroll
        for (int j = 0; j < 8; ++j) acc0[j] = (f2)0.f;

#pragma unroll
        for (int st = 0; st < 8; ++st) {            // 8 dims per step
            const int c0 = st * 8;

            // z row-pair, dims c0..c0+7: 2 x ds_read_b128 (8-phase, conflict-free)
            float4 za = *(const float4*)&zsh[zoff + 2 * c0];
            float4 zb = *(const float4*)&zsh[zoff + 2 * c0 + 4];
            float4 zc = *(const float4*)&zsh[zoff + 2 * c0 + 8];
            float4 zd = *(const float4*)&zsh[zoff + 2 * c0 + 12];
            f2 zp0; zp0.x = za.x; zp0.y = za.y;     // pair @ dim c0
            f2 zp1; zp1.x = za.z; zp1.y = za.w;     // dim c0+1
            f2 zp2; zp2.x = zb.x; zp2.y = zb.y;     // dim c0+2
            f2 zp3; zp3.x = zb.z; zp3.y = zb.w;     // dim c0+3
            f2 zp4; zp4.x = zc.x; zp4.y = zc.y;     // dim c0+4
            f2 zp5; zp5.x = zc.z; zp5.y = zc.w;     // dim c0+5
            f2 zp6; zp6.x = zd.x; zp6.y = zd.y;     // dim c0+6
            f2 zp7; zp7.x = zd.z; zp7.y = zd.w;     // dim c0+7

#pragma unroll
            for (int j = 0; j < 8; ++j) {
                // wave-uniform, adjacent dwordx4 pair -> merge toward dwordx8;
                // 32 B scalar load feeds 8 fma2 (32 VALU cyc)
                const float4 w0 = *(const float4*)(wk + (size_t)j * CDIM + c0);
                const float4 w1 = *(const float4*)(wk + (size_t)j * CDIM + c0 + 4);
                // dims ascending (c0..c0+7) -> sequential chain per (row, code)
                acc0[j] = fma2(zp0, (f2)(w0.x), acc0[j]);
                acc0[j] = fma2(zp1, (f2)(w0.y), acc0[j]);
                acc0[j] = fma2(zp2, (f2)(w0.z), acc0[j]);
                acc0[j] = fma2(zp3, (f2)(w0.w), acc0[j]);
                acc0[j] = fma2(zp4, (f2)(w1.x), acc0[j]);
                acc0[j] = fma2(zp5, (f2)(w1.y), acc0[j]);
                acc0[j] = fma2(zp6, (f2)(w1.z), acc0[j]);
                acc0[j] = fma2(zp7, (f2)(w1.w), acc0[j]);
            }
        }

        // d = fp32((S + b) - 2*C); strict < keeps earliest k (k ascending)
        const float4 bq0 = *(const float4*)(bsum + k0);      // uniform -> s_load
        const float4 bq1 = *(const float4*)(bsum + k0 + 4);
#pragma unroll
        for (int j = 0; j < 8; ++j) {
            float bj = j < 4 ? fc(bq0, j) : fc(bq1, j - 4);
            f2 bb2 = (f2)(bj);
            f2 dA = (Sp + bb2) - (acc0[j] + acc0[j]);
            int kg = k0 + j;
            if (dA.x < dmin0) { dmin0 = dA.x; kmin0 = kg; }
            if (dA.y < dmin1) { dmin1 = dA.y; kmin1 = kg; }
        }
    }

    // ---- merge per-row argmin across the 4 waves (packed key, LDS atomic) ----
    atomicMin(&skey[2 * l],     ((unsigned long long)__float_as_uint(dmin0) << 32) | (unsigned int)kmin0);
    atomicMin(&skey[2 * l + 1], ((unsigned long long)__float_as_uint(dmin1) << 32) | (unsigned int)kmin1);
    __syncthreads();

    // ---- epilogue ----
    if (t < 128)
        out[OUT_IDX + (size_t)bb * 128 + t] = (float)(int)(skey[t] & 0xFFFFFFFFull);

    double lacc = 0.0;
#pragma unroll
    for (int m = 0; m < 32; ++m) {
        int i = m * 256 + t;                        // 0..8191
        int c = i >> 7;                             // 0..63
        int r = i & 127;
        int kq = (int)(skey[r] & 0xFFFFFFFFull);
        float zv = zsh[(r >> 1) * PSTR + (r & 1) + 2 * c];
        float q  = w[(size_t)kq * CDIM + c];
        float d1  = __fsub_rn(q, zv);               // quantized - zp
        float val = __fadd_rn(zv, d1);              // zp + (q - zp)
        out[OUT_Q + zbase + (size_t)c * 4096 + r] = val;
        lacc += (double)__fmul_rn(d1, d1);
    }

#pragma unroll
    for (int off = 1; off < 64; off <<= 1) lacc += __shfl_xor(lacc, off, 64);
    if ((t & 63) == 0) lred[t >> 6] = lacc;
    __syncthreads();
    if (t == 0) {
        double tot = lred[0] + lred[1] + lred[2] + lred[3];
        partial[bb] = (float)(tot * (0.25 / 8388608.0));
    }
}

// ---------------- kernel C: reduce loss partials (1024) ----------------
__global__ __launch_bounds__(256) void vq_loss(const float* __restrict__ partial,
                                               float* __restrict__ out) {
    int t = threadIdx.x;
    double s = 0.0;
#pragma unroll
    for (int m = 0; m < 4; ++m) s += (double)partial[t + 256 * m];
#pragma unroll
    for (int off = 1; off < 64; off <<= 1) s += __shfl_xor(s, off, 64);
    __shared__ double sr[4];
    if ((t & 63) == 0) sr[t >> 6] = s;
    __syncthreads();
    if (t == 0) out[OUT_LOSS] = (float)(sr[0] + sr[1] + sr[2] + sr[3]);
}

extern "C" void kernel_launch(void* const* d_in, const int* in_sizes, int n_in,
                              void* d_out, int out_size, void* d_ws, size_t ws_size,
                              hipStream_t stream) {
    (void)in_sizes; (void)n_in; (void)out_size; (void)ws_size;
    const float* z = (const float*)d_in[0];
    const float* w = (const float*)d_in[1];
    float* out     = (float*)d_out;

    float* bsum    = (float*)d_ws;                  // 2048 floats
    float* partial = bsum + KCODES;                 // 1024 floats

    vq_bsum<<<8, 256, 0, stream>>>(w, bsum);
    vq_main<<<1024, 256, 0, stream>>>(z, w, bsum, out, partial);
    vq_loss<<<1, 256, 0, stream>>>(partial, out);
}

// Round 9
// 707.299 us; speedup vs baseline: 4.0560x; 1.0468x over previous
//
#include <hip/hip_runtime.h>

// VectorQuantizer: z (32,64,64,64) fp32, embedding_w (2048,64) fp32.
// Outputs concat: quantized_out (32,64,64,64) | indices (32,64,64) as float | loss (1)
//
// Numerics: bit-exact replication of the numpy fp32 reference (verified R1-R8, absmax 0):
//   S_n = pairwise64(z_n^2), b_k = pairwise64(w_k^2)  (numpy pairwise_sum order)
//   C_nk = one sequential fp32 FMA chain over c=0..63 ascending per (n,k)
//   d = fp32(fp32(S + b) - fp32(2*C)), argmin first-index tie-break (acc+acc == 2*C exactly).
//
// R9: K-loop touches NO LDS and no per-lane VMEM.
//  - lane owns one full z row in 64 VGPRs (loaded once, coalesced, used by the
//    pre-loop S computation so they cannot sink into the loop). w lives in
//    SGPRs via wave-uniform s_load. VGPR ~90 (R3's spill was w-in-VGPR + a
//    launch-bounds cap, not inherent).
//  - block = 128 rows: waves {0,2} own the rows with code-half 0, waves {1,3}
//    same rows with code-half 1 -> a CU holds only 2 distinct 2KB w-streams
//    (fits scalar cache; R4/R7/R8 held 4-8 -> sK$ thrash was the 33-45% idle).
//  - 8 codes in flight (8 independent 64-fma chains) for ILP; scalar v_fma
//    v,v,s,v. Per code: 16 adjacent s_load_dwordx4 (merge to dwordx16).
//  - 2-way argmin merge via packed-key (d_bits<<32|k) LDS atomicMin (R3-proven),
//    epilogue on the khalf-0 waves (z still in registers).
// Lessons kept: no launch-bounds squeeze (R3/R6), no arrays of loaded data
// (R5/R6), w only at provably wave-uniform addresses (R5).

#define KCODES   2048
#define CDIM     64
#define OUT_Q    0
#define OUT_IDX  8388608
#define OUT_LOSS 8519680

__device__ __forceinline__ float pairwise64(const float a[64]) {
    float r[8];
#pragma unroll
    for (int j = 0; j < 8; ++j) r[j] = a[j];
#pragma unroll
    for (int m = 1; m < 8; ++m)
#pragma unroll
        for (int j = 0; j < 8; ++j) r[j] = __fadd_rn(r[j], a[m * 8 + j]);
    float s01 = __fadd_rn(r[0], r[1]);
    float s23 = __fadd_rn(r[2], r[3]);
    float s45 = __fadd_rn(r[4], r[5]);
    float s67 = __fadd_rn(r[6], r[7]);
    return __fadd_rn(__fadd_rn(s01, s23), __fadd_rn(s45, s67));
}

// ---------------- kernel A: b_k = pairwise64(w_k^2) ----------------
__global__ __launch_bounds__(256) void vq_bsum(const float* __restrict__ w,
                                               float* __restrict__ bsum) {
    int k = blockIdx.x * 256 + threadIdx.x;
    const float4* wr = (const float4*)(w + (size_t)k * CDIM);
    float a[64];
#pragma unroll
    for (int m = 0; m < 16; ++m) {
        float4 v = wr[m];
        a[4 * m + 0] = __fmul_rn(v.x, v.x);
        a[4 * m + 1] = __fmul_rn(v.y, v.y);
        a[4 * m + 2] = __fmul_rn(v.z, v.z);
        a[4 * m + 3] = __fmul_rn(v.w, v.w);
    }
    bsum[k] = pairwise64(a);
}

// ---------------- kernel B: main VQ (fused argmin + epilogue) ----------------
// grid 1024 x 256 thr. Block = 128 rows. Wave id wv = t>>6:
//   rowgrp = wv>>1 (0/1), khalf = wv&1. Lane l owns row rowgrp*64+l,
//   sweeping codes [khalf*1024, +1024).
__global__ __launch_bounds__(256, 2) void vq_main(const float* __restrict__ z,
                                                  const float* __restrict__ w,
                                                  const float* __restrict__ bsum,
                                                  float* __restrict__ out,
                                                  float* __restrict__ partial) {
    __shared__ unsigned long long skey[128];
    __shared__ double lred[2];

    const int t  = threadIdx.x;
    const int l  = t & 63;
    const int wv = t >> 6;
    const int rowgrp = wv >> 1;
    const int bb = blockIdx.x;                      // 0..1023; rows [bb*128, +128)
    const size_t zbase = (size_t)(bb >> 5) * 262144 + (size_t)(bb & 31) * 128;
    const int ro = rowgrp * 64 + l;                 // row within block

    if (t < 128) skey[t] = 0xFFFFFFFFFFFFFFFFull;

    // ---- load my row into VGPRs (coalesced: lanes = consecutive rows) ----
    const float* zp = z + zbase + ro;
    float zr[64];
#pragma unroll
    for (int c = 0; c < 64; ++c) zr[c] = zp[(size_t)c * 4096];

    // ---- S = numpy-pairwise sum of squares (also pins zr before the loop) ----
    float a[64];
#pragma unroll
    for (int c = 0; c < 64; ++c) a[c] = __fmul_rn(zr[c], zr[c]);
    const float S = pairwise64(a);

    __syncthreads();                                // skey init visible to all

    // wave-uniform code half: waves {0,2} -> 0, {1,3} -> 1024
    const int kbase = __builtin_amdgcn_readfirstlane(wv & 1) * 1024;
    const float* wk = w + (size_t)kbase * CDIM;

    float dmin = __builtin_inff();
    int   kmin = 0;

    for (int ks = 0; ks < 128; ++ks) {              // 8 codes per iteration
        const int k0 = kbase + ks * 8;
        const float* w8 = wk + (size_t)ks * (8 * CDIM);

        float acc[8];
#pragma unroll
        for (int j = 0; j < 8; ++j) acc[j] = 0.f;

#pragma unroll
        for (int j = 0; j < 8; ++j) {
#pragma unroll
            for (int cq = 0; cq < 16; ++cq) {
                // wave-uniform adjacent dwordx4 -> merged s_load_dwordx16;
                // short-lived temp (never an array of loaded data)
                const float4 wc = *(const float4*)(w8 + (size_t)j * CDIM + cq * 4);
                // dims ascending -> one sequential chain per (row, code)
                acc[j] = __builtin_fmaf(zr[4 * cq + 0], wc.x, acc[j]);
                acc[j] = __builtin_fmaf(zr[4 * cq + 1], wc.y, acc[j]);
                acc[j] = __builtin_fmaf(zr[4 * cq + 2], wc.z, acc[j]);
                acc[j] = __builtin_fmaf(zr[4 * cq + 3], wc.w, acc[j]);
            }
        }

        // d = fp32((S + b) - (acc+acc)); strict < keeps earliest k
#pragma unroll
        for (int j = 0; j < 8; ++j) {
            const float bj = bsum[k0 + j];          // uniform -> s_load
            const float d = __fsub_rn(__fadd_rn(S, bj), __fadd_rn(acc[j], acc[j]));
            if (d < dmin) { dmin = d; kmin = k0 + j; }
        }
    }

    // ---- merge the two code-halves per row (packed key, LDS atomicMin) ----
    atomicMin(&skey[ro],
              ((unsigned long long)__float_as_uint(dmin) << 32) | (unsigned int)kmin);
    __syncthreads();

    // ---- epilogue: khalf-0 waves own their rows (z still in registers) ----
    double lacc = 0.0;
    if ((wv & 1) == 0) {
        const int kq = (int)(skey[ro] & 0xFFFFFFFFull);
        out[OUT_IDX + (size_t)bb * 128 + ro] = (float)kq;
        const float* wq = w + (size_t)kq * CDIM;
#pragma unroll
        for (int c = 0; c < 64; ++c) {
            const float zv = zr[c];
            const float q  = wq[c];
            const float d1  = __fsub_rn(q, zv);     // quantized - zp
            const float val = __fadd_rn(zv, d1);    // zp + (q - zp)
            out[OUT_Q + zbase + (size_t)c * 4096 + ro] = val;
            lacc += (double)__fmul_rn(d1, d1);
        }
    }

    // reduce loss over the two khalf-0 waves
#pragma unroll
    for (int off = 1; off < 64; off <<= 1) lacc += __shfl_xor(lacc, off, 64);
    if ((wv & 1) == 0 && l == 0) lred[rowgrp] = lacc;
    __syncthreads();
    if (t == 0)
        partial[bb] = (float)((lred[0] + lred[1]) * (0.25 / 8388608.0));
}

// ---------------- kernel C: reduce loss partials (1024) ----------------
__global__ __launch_bounds__(256) void vq_loss(const float* __restrict__ partial,
                                               float* __restrict__ out) {
    int t = threadIdx.x;
    double s = 0.0;
#pragma unroll
    for (int m = 0; m < 4; ++m) s += (double)partial[t + 256 * m];
#pragma unroll
    for (int off = 1; off < 64; off <<= 1) s += __shfl_xor(s, off, 64);
    __shared__ double sr[4];
    if ((t & 63) == 0) sr[t >> 6] = s;
    __syncthreads();
    if (t == 0) out[OUT_LOSS] = (float)(sr[0] + sr[1] + sr[2] + sr[3]);
}

extern "C" void kernel_launch(void* const* d_in, const int* in_sizes, int n_in,
                              void* d_out, int out_size, void* d_ws, size_t ws_size,
                              hipStream_t stream) {
    (void)in_sizes; (void)n_in; (void)out_size; (void)ws_size;
    const float* z = (const float*)d_in[0];
    const float* w = (const float*)d_in[1];
    float* out     = (float*)d_out;

    float* bsum    = (float*)d_ws;                  // 2048 floats
    float* partial = bsum + KCODES;                 // 1024 floats

    vq_bsum<<<8, 256, 0, stream>>>(w, bsum);
    vq_main<<<1024, 256, 0, stream>>>(z, w, bsum, out, partial);
    vq_loss<<<1, 256, 0, stream>>>(partial, out);
}